// Round 5
// baseline (342.234 us; speedup 1.0000x reference)
//
#include <hip/hip_runtime.h>
#include <hip/hip_bf16.h>
#include <stdint.h>

typedef __attribute__((ext_vector_type(8))) short short8;
typedef __attribute__((ext_vector_type(4))) short short4v;
typedef __attribute__((ext_vector_type(4))) float f32x4;

__device__ inline unsigned short f2bf(float f) {
    union { float f; uint32_t u; } v; v.f = f;
    uint32_t u = v.u;
    uint32_t r = (u + 0x7FFFu + ((u >> 16) & 1u)) >> 16;   // RNE
    return (unsigned short)r;
}

__device__ inline short8 pk8(float4 a, float4 b) {
    short8 r;
    r[0] = (short)f2bf(a.x); r[1] = (short)f2bf(a.y);
    r[2] = (short)f2bf(a.z); r[3] = (short)f2bf(a.w);
    r[4] = (short)f2bf(b.x); r[5] = (short)f2bf(b.y);
    r[6] = (short)f2bf(b.z); r[7] = (short)f2bf(b.w);
    return r;
}

// ---------------- Router kernel 1: partial GEMM  h_pre = g_in @ W1 -------------
// 4 j/thread (acc[16] x f32x4): FMA-bound. W1 loads per-thread float4
// (coalesced), software-pipelined one oct ahead. k-split 64 -> 512 blocks (2/CU).
// Decode bits: [0]=jc, [1:2]=ks-low, [3:4]=bg, [5:8]=ks-high; the 4 bg-siblings
// sharing a W1 slice have equal g%8 -> same XCD -> L2 hit after first touch.
__global__ __launch_bounds__(256) void router1(const float* __restrict__ DKP,
                                               const float* __restrict__ W1,
                                               float* __restrict__ part) {
    __shared__ float gin[16 * 64];   // 4 KB
    const int t  = threadIdx.x;
    const int g  = blockIdx.x;                        // 0..511
    const int jc = g & 1;
    const int bg = (g >> 3) & 3;
    const int ks = ((g >> 1) & 3) | ((g >> 5) << 2);  // 0..63
    const int k0 = ks * 64;
    {   // stage g_in chunk [16 b][64 k]
        const int bl = t >> 4, q = t & 15;
        *(float4*)(gin + bl * 64 + q * 4) =
            *(const float4*)(DKP + (size_t)(bg * 16 + bl) * 4096 + k0 + q * 4);
    }
    __syncthreads();
    const int ja = jc * 1024 + t * 4;   // 4 contiguous j per thread
    f32x4 acc[16];
    #pragma unroll
    for (int bl = 0; bl < 16; ++bl) acc[bl] = (f32x4){0.f, 0.f, 0.f, 0.f};
    f32x4 wcur[8], wnxt[8];
    #pragma unroll
    for (int i = 0; i < 8; ++i)
        wcur[i] = *(const f32x4*)(W1 + (size_t)(k0 + i) * 2048 + ja);
    #pragma unroll 1
    for (int oct = 0; oct < 8; ++oct) {
        const int kk = oct * 8;
        if (oct < 7) {
            #pragma unroll
            for (int i = 0; i < 8; ++i)
                wnxt[i] = *(const f32x4*)(W1 + (size_t)(k0 + kk + 8 + i) * 2048 + ja);
        }
        #pragma unroll
        for (int bl = 0; bl < 16; ++bl) {
            float4 g0 = *(const float4*)(gin + bl * 64 + kk);
            float4 g1 = *(const float4*)(gin + bl * 64 + kk + 4);
            f32x4 a = acc[bl];
            a = a + wcur[0] * g0.x + wcur[1] * g0.y + wcur[2] * g0.z + wcur[3] * g0.w
                  + wcur[4] * g1.x + wcur[5] * g1.y + wcur[6] * g1.z + wcur[7] * g1.w;
            acc[bl] = a;
        }
        #pragma unroll
        for (int i = 0; i < 8; ++i) wcur[i] = wnxt[i];
    }
    #pragma unroll 1
    for (int bl = 0; bl < 16; ++bl)
        *(f32x4*)(part + ((size_t)(ks * 64 + bg * 16 + bl)) * 2048 + ja) = acc[bl];
}

// ---------------- Router 2 (parallel): reduce splits + GELU + partial logits --
__global__ __launch_bounds__(256) void router2p(const float* __restrict__ part,
                                                const float* __restrict__ cyc,
                                                const float* __restrict__ W1,
                                                const float* __restrict__ b1,
                                                const float* __restrict__ W2,
                                                float* __restrict__ plog) {
    __shared__ float red[256 * 8];
    const int b = blockIdx.x, jc = blockIdx.y;
    const int t = threadIdx.x;
    const int j = jc * 256 + t;
    float s = 0.f;
    #pragma unroll 8
    for (int tt = 0; tt < 64; ++tt)
        s += part[((size_t)tt * 64 + b) * 2048 + j];
    s += cyc[b] * W1[(size_t)4096 * 2048 + j] + b1[j];
    // jax.nn.gelu default (tanh approximation)
    const float u  = s + 0.044715f * s * s * s;
    const float th = tanhf(0.7978845608028654f * u);
    const float hv = 0.5f * s * (1.0f + th);
    const float* w = W2 + (size_t)j * 8;
    #pragma unroll
    for (int e = 0; e < 8; ++e) red[t * 8 + e] = hv * w[e];
    __syncthreads();
    if (t < 8) {
        float acc = 0.f;
        for (int r = 0; r < 256; ++r) acc += red[r * 8 + t];
        plog[((size_t)b * 8 + jc) * 8 + t] = acc;
    }
}

// ---------------- Router 4: final logits + top-2 + softmax + renorm gates -----
__global__ __launch_bounds__(64) void router4(const float* __restrict__ plog,
                                              const float* __restrict__ b2,
                                              float4* __restrict__ gates) {
    const int b = threadIdx.x;
    float l[8];
    #pragma unroll
    for (int e = 0; e < 8; ++e) l[e] = b2[e];
    #pragma unroll
    for (int jc = 0; jc < 8; ++jc)
        #pragma unroll
        for (int e = 0; e < 8; ++e)
            l[e] += plog[((size_t)b * 8 + jc) * 8 + e];
    int e0 = 0;
    #pragma unroll
    for (int e = 1; e < 8; ++e) if (l[e] > l[e0]) e0 = e;
    int e1 = (e0 == 0) ? 1 : 0;
    #pragma unroll
    for (int e = 0; e < 8; ++e) if (e != e0 && l[e] > l[e1]) e1 = e;
    const float m = l[e0];
    float p[8], Z = 0.f;
    #pragma unroll
    for (int e = 0; e < 8; ++e) { p[e] = expf(l[e] - m); Z += p[e]; }
    const float pe0 = p[e0] / Z, pe1 = p[e1] / Z;
    const float s2 = pe0 + pe1 + 1e-9f;
    gates[b] = make_float4(__int_as_float(e0), __int_as_float(e1), pe0 / s2, pe1 / s2);
}

// ---------------- Combine weights -> k-tiled layout --------------------------
// wc[b][kt][n][ksub]: [64][29][512][32] bf16 — each GEMM k-step's B-tile is one
// contiguous 32 KB slab. [32i x 32d] tiles; stage genW + all 8 expert tiles
// transposed in LDS once. R5: battery loop split 4-way across blockIdx.z
// (grid 1856, 16 batteries/block) — the 64-iter serial chain per block was the
// suspected latency floor; 4x more blocks also overlaps staging with stores.
__global__ __launch_bounds__(256) void combine_w(const float* __restrict__ genW,
                                                 const float* __restrict__ expW,
                                                 const float4* __restrict__ gates,
                                                 unsigned short* __restrict__ wc) {
    __shared__ float T[9][32 * 36];   // [src][d_loc][i_loc], pad 36
    __shared__ float4 gsh[64];
    const int t  = threadIdx.x;
    const int d0 = blockIdx.x * 32;
    const int kt = blockIdx.y;
    const int i0 = kt * 32;
    const int bz = blockIdx.z;          // 16-battery group
    if (t < 64) gsh[t] = gates[t];
    {
        const int il = t >> 3, d4 = (t & 7) * 4;
        const int i = i0 + il;
        const bool valid = (i < 900);
        const size_t off = (size_t)i * 512 + d0 + d4;
        #pragma unroll
        for (int s = 0; s < 9; ++s) {
            const float* src = (s == 0) ? genW : (expW + (size_t)(s - 1) * 900 * 512);
            float4 v = valid ? *(const float4*)(src + off) : make_float4(0, 0, 0, 0);
            float* Td = &T[s][0];
            Td[(d4 + 0) * 36 + il] = v.x;
            Td[(d4 + 1) * 36 + il] = v.y;
            Td[(d4 + 2) * 36 + il] = v.z;
            Td[(d4 + 3) * 36 + il] = v.w;
        }
    }
    __syncthreads();
    const int bb = t >> 7;              // 0/1: which battery of the pair
    const int dl = (t >> 2) & 31;       // n-row (d_model dim)
    const int sg = t & 3;               // i-segment (8 i each)
    const int fo = dl * 36 + sg * 8;
    unsigned short* wrow = wc + (size_t)kt * 16384 + (d0 + dl) * 32 + sg * 8;
    #pragma unroll 2
    for (int bp = 0; bp < 8; ++bp) {
        const int b = bz * 16 + bp * 2 + bb;
        const float4 gt = gsh[b];
        const int e0 = __float_as_int(gt.x), e1 = __float_as_int(gt.y);
        const float g0 = gt.z, g1 = gt.w;
        float4 Ga = *(const float4*)&T[0][fo],      Gb = *(const float4*)&T[0][fo + 4];
        float4 Xa = *(const float4*)&T[1 + e0][fo], Xb = *(const float4*)&T[1 + e0][fo + 4];
        float4 Ya = *(const float4*)&T[1 + e1][fo], Yb = *(const float4*)&T[1 + e1][fo + 4];
        short8 r;
        r[0] = (short)f2bf(Ga.x + g0 * Xa.x + g1 * Ya.x);
        r[1] = (short)f2bf(Ga.y + g0 * Xa.y + g1 * Ya.y);
        r[2] = (short)f2bf(Ga.z + g0 * Xa.z + g1 * Ya.z);
        r[3] = (short)f2bf(Ga.w + g0 * Xa.w + g1 * Ya.w);
        r[4] = (short)f2bf(Gb.x + g0 * Xb.x + g1 * Yb.x);
        r[5] = (short)f2bf(Gb.y + g0 * Xb.y + g1 * Yb.y);
        r[6] = (short)f2bf(Gb.z + g0 * Xb.z + g1 * Yb.z);
        r[7] = (short)f2bf(Gb.w + g0 * Xb.w + g1 * Yb.w);
        *(short8*)(wrow + (size_t)b * 475136) = r;
    }
}

// ---------------- Main fused batched GEMM: out[b] = x[b] @ Wcomb_b + bias ------
// R5: BN=256 (was 512) to restore 2 blocks/CU. R4 hit 82 us at 1 block/CU with
// NOTHING busy (Mfma 14 / VALU 8.5 / HBM 24 / Occ 20%): the 2-phase per-k-step
// drain is naked without a co-resident block to overlap it (m114 mechanism —
// what R0-R2 had at 2 blocks/CU). LDS 53 KB -> 2 blocks/CU; grid 512 = 64 b x
// 4 m x 2 n. Extra x re-read (x2) and wcomb windows are L2-resident per XCD
// (~0.8 MB live set), so HBM FETCH should be ~unchanged. Wave = 64m x 64n,
// acc[4][4] (64 VGPR) -> fits the 128-VGPR cap of __launch_bounds__(512,4).
// Decode keeps all 8 (m,n) pieces of a battery on one XCD (g%8 invariant).
__global__ __launch_bounds__(512, 4) void moe_gemm(const float* __restrict__ x,
                                                   const unsigned short* __restrict__ wc,
                                                   const float4* __restrict__ gates,
                                                   const float* __restrict__ eb,
                                                   const float* __restrict__ genb,
                                                   float* __restrict__ out) {
    __shared__ unsigned short As[2][128 * 40];   // [m][k] bf16, stride 40 (20 KB)
    __shared__ unsigned short Bs[2][256 * 32];   // [n][k] bf16, slot-swizzled (32 KB)
    const int g   = blockIdx.x;                  // 0..511
    const int b   = (g & 7) + 8 * (g >> 6);
    const int rem = (g >> 3) & 7;
    const int m0  = (rem >> 1) * 128;
    const int n0  = (rem & 1) * 256;
    const int t = threadIdx.x, lane = t & 63, wid = t >> 6;
    const float4 gt = gates[b];
    const int e0 = __float_as_int(gt.x), e1 = __float_as_int(gt.y);
    const float g0 = gt.z, g1 = gt.w;
    const float* xb = x + (size_t)b * 512 * 900;
    const unsigned short* wcb = wc + (size_t)b * 475136;
    f32x4 acc[4][4];
    #pragma unroll
    for (int mi = 0; mi < 4; ++mi)
        #pragma unroll
        for (int ni = 0; ni < 4; ++ni)
            acc[mi][ni] = (f32x4){0.f, 0.f, 0.f, 0.f};

    // A staging: thread -> row t>>2 (128 rows), 8 floats at (t&3)*8
    const int arow = t >> 2;
    const int acol = (t & 3) * 8;
    const float* xrow = xb + (size_t)(m0 + arow) * 900 + acol;
    // B staging: lane -> row u=lane>>2 in 16-row chunk; slot=lane&3 holds
    // global seg = slot ^ ((u>>1)&3) = slot ^ ((lane>>3)&3)
    const int bseg  = (lane & 3) ^ ((lane >> 3) & 3);
    const int burow = lane >> 2;

    const int wm = wid >> 2;            // 0..1 : m-half of wave
    const int wn = (wid & 3) * 64;      // n-origin of wave within 256
    const int lm = lane & 15, lq = lane >> 4;

    auto stageB = [&](int buf, int kt) {
        const unsigned short* slab = wcb + (size_t)kt * 16384;
        #pragma unroll
        for (int r = 0; r < 2; ++r) {
            const int chunk = wid * 2 + r;           // 0..15 (16 rows each)
            const unsigned short* gsrc = slab + (size_t)(n0 + chunk * 16 + burow) * 32 + bseg * 8;
            unsigned short* ldst = &Bs[buf][chunk * 512];
            __builtin_amdgcn_global_load_lds(
                (const __attribute__((address_space(1))) unsigned int*)gsrc,
                (__attribute__((address_space(3))) unsigned int*)ldst, 16, 0, 0);
        }
    };
    auto loadA = [&](int kt, float4& lo, float4& hi) {
        if (kt < 28) {
            lo = *(const float4*)(xrow + kt * 32);
            hi = *(const float4*)(xrow + kt * 32 + 4);
        } else {   // k = 896 + acol..: valid only for acol==0 (floats 896..899)
            lo = make_float4(0.f, 0.f, 0.f, 0.f);
            hi = make_float4(0.f, 0.f, 0.f, 0.f);
            if (acol == 0) lo = *(const float4*)(xb + (size_t)(m0 + arow) * 900 + 896);
        }
    };
    auto packA = [&](int buf, float4 lo, float4 hi) {
        *(short8*)&As[buf][arow * 40 + acol] = pk8(lo, hi);
    };
    auto compute = [&](int buf) {
        short8 af[4];
        #pragma unroll
        for (int mi = 0; mi < 4; ++mi)
            af[mi] = *(const short8*)&As[buf][(wm * 64 + mi * 16 + lm) * 40 + lq * 8];
        #pragma unroll
        for (int ni = 0; ni < 4; ++ni) {
            const int n = wn + ni * 16 + lm;
            const int slot = lq ^ ((lm >> 1) & 3);
            short8 bf = *(const short8*)&Bs[buf][n * 32 + slot * 8];
            #pragma unroll
            for (int mi = 0; mi < 4; ++mi)
                acc[mi][ni] = __builtin_amdgcn_mfma_f32_16x16x32_bf16(
                    af[mi], bf, acc[mi][ni], 0, 0, 0);
        }
    };

    // ---- prologue: stage kt=0 into buf 0
    {
        float4 lo, hi;
        loadA(0, lo, hi);
        stageB(0, 0);
        packA(0, lo, hi);
        __syncthreads();
    }
    // ---- main loop: 28 staging steps, hand-unrolled x2 for buffer constants.
    // Per step: issue A(t+1) + B(t+1) loads, compute(t) (loads fly underneath),
    // pack A, barrier. The per-step drain overlaps the co-resident block's
    // compute (2 blocks/CU).
    #pragma unroll 1
    for (int p = 0; p < 14; ++p) {
        {
            float4 lo, hi;
            loadA(2 * p + 1, lo, hi);
            stageB(1, 2 * p + 1);
            compute(0);
            packA(1, lo, hi);
            __syncthreads();
        }
        {
            float4 lo, hi;
            loadA(2 * p + 2, lo, hi);
            stageB(0, 2 * p + 2);
            compute(1);
            packA(0, lo, hi);
            __syncthreads();
        }
    }
    // ---- final step kt=28 from buf 0
    compute(0);

    // ---- Epilogue: add gen_b + g0*eb[e0] + g1*eb[e1], store f32
    #pragma unroll
    for (int ni = 0; ni < 4; ++ni) {
        const int col = n0 + wn + ni * 16 + lm;
        const float bias = genb[col] + g0 * eb[e0 * 512 + col] + g1 * eb[e1 * 512 + col];
        #pragma unroll
        for (int mi = 0; mi < 4; ++mi) {
            const int row = m0 + wm * 64 + mi * 16 + lq * 4;
            #pragma unroll
            for (int r = 0; r < 4; ++r)
                out[((size_t)b * 512 + row + r) * 512 + col] = acc[mi][ni][r] + bias;
        }
    }
}

extern "C" void kernel_launch(void* const* d_in, const int* in_sizes, int n_in,
                              void* d_out, int out_size, void* d_ws, size_t ws_size,
                              hipStream_t stream) {
    const float* x    = (const float*)d_in[0];   // [64][512][900]
    const float* cyc  = (const float*)d_in[1];   // [64][1]
    const float* dkp  = (const float*)d_in[2];   // [64][4096]
    const float* gW1  = (const float*)d_in[3];   // [4097][2048]
    const float* gb1  = (const float*)d_in[4];   // [2048]
    const float* gW2  = (const float*)d_in[5];   // [2048][8]
    const float* gb2  = (const float*)d_in[6];   // [8]
    const float* eW   = (const float*)d_in[7];   // [8][900][512]
    const float* eb   = (const float*)d_in[8];   // [8][512]
    const float* genW = (const float*)d_in[9];   // [900][512]
    const float* genb = (const float*)d_in[10];  // [512]
    float* out = (float*)d_out;                  // [64][512][512] f32

    char* ws = (char*)d_ws;
    const size_t WCOMB_BYTES = 60817408ull;              // [64][29][512][32] bf16
    const size_t PART_BYTES  = 64ull * 64 * 2048 * 4;    // 33.5 MB
    unsigned short* wcomb = (unsigned short*)ws;
    float* part; float4* gts; float* plog;
    if (ws_size >= WCOMB_BYTES + PART_BYTES + (1u << 20)) {
        // R5: un-alias part from wcomb — router1 dirties these lines on every
        // XCD's L2; combine_w rewriting the same lines from other XCDs risks
        // cross-L2 dirty-line ping-pong. Separate regions when ws allows.
        part = (float*)(ws + WCOMB_BYTES);
        gts  = (float4*)(ws + WCOMB_BYTES + PART_BYTES);
        plog = (float*)(ws + WCOMB_BYTES + PART_BYTES + 1024);
    } else {
        // fallback: partials alias wcomb (dead before combine_w runs)
        part = (float*)ws;
        gts  = (float4*)(ws + WCOMB_BYTES);
        plog = (float*)(ws + WCOMB_BYTES + 1024);
    }

    router1<<<512, 256, 0, stream>>>(dkp, gW1, part);
    router2p<<<dim3(64, 8), 256, 0, stream>>>(part, cyc, gW1, gb1, gW2, plog);
    router4<<<1, 64, 0, stream>>>(plog, gb2, gts);
    combine_w<<<dim3(16, 29, 4), 256, 0, stream>>>(genW, eW, gts, wcomb);
    moe_gemm<<<512, 512, 0, stream>>>(x, wcomb, gts, eb, genb, out);
}

// Round 6
// 322.871 us; speedup vs baseline: 1.0600x; 1.0600x over previous
//
#include <hip/hip_runtime.h>
#include <hip/hip_bf16.h>
#include <stdint.h>

typedef __attribute__((ext_vector_type(8))) short short8;
typedef __attribute__((ext_vector_type(4))) short short4v;
typedef __attribute__((ext_vector_type(4))) float f32x4;

__device__ inline unsigned short f2bf(float f) {
    union { float f; uint32_t u; } v; v.f = f;
    uint32_t u = v.u;
    uint32_t r = (u + 0x7FFFu + ((u >> 16) & 1u)) >> 16;   // RNE
    return (unsigned short)r;
}

__device__ inline short8 pk8(float4 a, float4 b) {
    short8 r;
    r[0] = (short)f2bf(a.x); r[1] = (short)f2bf(a.y);
    r[2] = (short)f2bf(a.z); r[3] = (short)f2bf(a.w);
    r[4] = (short)f2bf(b.x); r[5] = (short)f2bf(b.y);
    r[6] = (short)f2bf(b.z); r[7] = (short)f2bf(b.w);
    return r;
}

// ---------------- Router kernel 1: partial GEMM  h_pre = g_in @ W1 -------------
// 4 j/thread (acc[16] x f32x4): FMA-bound. W1 loads per-thread float4
// (coalesced), software-pipelined one oct ahead. k-split 64 -> 512 blocks (2/CU).
// Decode bits: [0]=jc, [1:2]=ks-low, [3:4]=bg, [5:8]=ks-high; the 4 bg-siblings
// sharing a W1 slice have equal g%8 -> same XCD -> L2 hit after first touch.
__global__ __launch_bounds__(256) void router1(const float* __restrict__ DKP,
                                               const float* __restrict__ W1,
                                               float* __restrict__ part) {
    __shared__ float gin[16 * 64];   // 4 KB
    const int t  = threadIdx.x;
    const int g  = blockIdx.x;                        // 0..511
    const int jc = g & 1;
    const int bg = (g >> 3) & 3;
    const int ks = ((g >> 1) & 3) | ((g >> 5) << 2);  // 0..63
    const int k0 = ks * 64;
    {   // stage g_in chunk [16 b][64 k]
        const int bl = t >> 4, q = t & 15;
        *(float4*)(gin + bl * 64 + q * 4) =
            *(const float4*)(DKP + (size_t)(bg * 16 + bl) * 4096 + k0 + q * 4);
    }
    __syncthreads();
    const int ja = jc * 1024 + t * 4;   // 4 contiguous j per thread
    f32x4 acc[16];
    #pragma unroll
    for (int bl = 0; bl < 16; ++bl) acc[bl] = (f32x4){0.f, 0.f, 0.f, 0.f};
    f32x4 wcur[8], wnxt[8];
    #pragma unroll
    for (int i = 0; i < 8; ++i)
        wcur[i] = *(const f32x4*)(W1 + (size_t)(k0 + i) * 2048 + ja);
    #pragma unroll 1
    for (int oct = 0; oct < 8; ++oct) {
        const int kk = oct * 8;
        if (oct < 7) {
            #pragma unroll
            for (int i = 0; i < 8; ++i)
                wnxt[i] = *(const f32x4*)(W1 + (size_t)(k0 + kk + 8 + i) * 2048 + ja);
        }
        #pragma unroll
        for (int bl = 0; bl < 16; ++bl) {
            float4 g0 = *(const float4*)(gin + bl * 64 + kk);
            float4 g1 = *(const float4*)(gin + bl * 64 + kk + 4);
            f32x4 a = acc[bl];
            a = a + wcur[0] * g0.x + wcur[1] * g0.y + wcur[2] * g0.z + wcur[3] * g0.w
                  + wcur[4] * g1.x + wcur[5] * g1.y + wcur[6] * g1.z + wcur[7] * g1.w;
            acc[bl] = a;
        }
        #pragma unroll
        for (int i = 0; i < 8; ++i) wcur[i] = wnxt[i];
    }
    #pragma unroll 1
    for (int bl = 0; bl < 16; ++bl)
        *(f32x4*)(part + ((size_t)(ks * 64 + bg * 16 + bl)) * 2048 + ja) = acc[bl];
}

// ---------------- Router 2 (parallel): reduce splits + GELU + partial logits --
__global__ __launch_bounds__(256) void router2p(const float* __restrict__ part,
                                                const float* __restrict__ cyc,
                                                const float* __restrict__ W1,
                                                const float* __restrict__ b1,
                                                const float* __restrict__ W2,
                                                float* __restrict__ plog) {
    __shared__ float red[256 * 8];
    const int b = blockIdx.x, jc = blockIdx.y;
    const int t = threadIdx.x;
    const int j = jc * 256 + t;
    float s = 0.f;
    #pragma unroll 8
    for (int tt = 0; tt < 64; ++tt)
        s += part[((size_t)tt * 64 + b) * 2048 + j];
    s += cyc[b] * W1[(size_t)4096 * 2048 + j] + b1[j];
    // jax.nn.gelu default (tanh approximation)
    const float u  = s + 0.044715f * s * s * s;
    const float th = tanhf(0.7978845608028654f * u);
    const float hv = 0.5f * s * (1.0f + th);
    const float* w = W2 + (size_t)j * 8;
    #pragma unroll
    for (int e = 0; e < 8; ++e) red[t * 8 + e] = hv * w[e];
    __syncthreads();
    if (t < 8) {
        float acc = 0.f;
        for (int r = 0; r < 256; ++r) acc += red[r * 8 + t];
        plog[((size_t)b * 8 + jc) * 8 + t] = acc;
    }
}

// ---------------- Combine weights -> k-tiled layout (gates fused in) ----------
// wc[b][kt][n][ksub]: [64][29][512][32] bf16 — each GEMM k-step's B-tile is one
// contiguous 32 KB slab. [32i x 32d] tiles; stage genW + all 8 expert tiles
// transposed in LDS once, loop 64 batteries (2/iter). R6: router4 FUSED — the
// first 64 threads recompute gates from plog (runs concurrently with the other
// threads' staging, zero marginal time); block (0,0) publishes gates for
// moe_gemm. Removes one serial kernel launch.
__global__ __launch_bounds__(256) void combine_w(const float* __restrict__ genW,
                                                 const float* __restrict__ expW,
                                                 const float* __restrict__ plog,
                                                 const float* __restrict__ b2,
                                                 float4* __restrict__ gts,
                                                 unsigned short* __restrict__ wc) {
    __shared__ float T[9][32 * 36];   // [src][d_loc][i_loc], pad 36
    __shared__ float4 gsh[64];
    const int t  = threadIdx.x;
    const int d0 = blockIdx.x * 32;
    const int kt = blockIdx.y;
    const int i0 = kt * 32;
    if (t < 64) {   // recompute gates for battery t (router4 logic, in-block)
        const int b = t;
        float l[8];
        #pragma unroll
        for (int e = 0; e < 8; ++e) l[e] = b2[e];
        #pragma unroll
        for (int jc = 0; jc < 8; ++jc)
            #pragma unroll
            for (int e = 0; e < 8; ++e)
                l[e] += plog[((size_t)b * 8 + jc) * 8 + e];
        int e0 = 0;
        #pragma unroll
        for (int e = 1; e < 8; ++e) if (l[e] > l[e0]) e0 = e;
        int e1 = (e0 == 0) ? 1 : 0;
        #pragma unroll
        for (int e = 0; e < 8; ++e) if (e != e0 && l[e] > l[e1]) e1 = e;
        const float m = l[e0];
        float p[8], Z = 0.f;
        #pragma unroll
        for (int e = 0; e < 8; ++e) { p[e] = expf(l[e] - m); Z += p[e]; }
        const float pe0 = p[e0] / Z, pe1 = p[e1] / Z;
        const float s2 = pe0 + pe1 + 1e-9f;
        float4 gv = make_float4(__int_as_float(e0), __int_as_float(e1), pe0 / s2, pe1 / s2);
        gsh[b] = gv;
        if (blockIdx.x == 0 && blockIdx.y == 0) gts[b] = gv;
    }
    {
        const int il = t >> 3, d4 = (t & 7) * 4;
        const int i = i0 + il;
        const bool valid = (i < 900);
        const size_t off = (size_t)i * 512 + d0 + d4;
        #pragma unroll
        for (int s = 0; s < 9; ++s) {
            const float* src = (s == 0) ? genW : (expW + (size_t)(s - 1) * 900 * 512);
            float4 v = valid ? *(const float4*)(src + off) : make_float4(0, 0, 0, 0);
            float* Td = &T[s][0];
            Td[(d4 + 0) * 36 + il] = v.x;
            Td[(d4 + 1) * 36 + il] = v.y;
            Td[(d4 + 2) * 36 + il] = v.z;
            Td[(d4 + 3) * 36 + il] = v.w;
        }
    }
    __syncthreads();
    const int bb = t >> 7;              // 0/1: which battery of the pair
    const int dl = (t >> 2) & 31;       // n-row (d_model dim)
    const int sg = t & 3;               // i-segment (8 i each)
    const int fo = dl * 36 + sg * 8;
    unsigned short* wrow = wc + (size_t)kt * 16384 + (d0 + dl) * 32 + sg * 8;
    #pragma unroll 2
    for (int bp = 0; bp < 32; ++bp) {
        const int b = bp * 2 + bb;
        const float4 gt = gsh[b];
        const int e0 = __float_as_int(gt.x), e1 = __float_as_int(gt.y);
        const float g0 = gt.z, g1 = gt.w;
        float4 Ga = *(const float4*)&T[0][fo],      Gb = *(const float4*)&T[0][fo + 4];
        float4 Xa = *(const float4*)&T[1 + e0][fo], Xb = *(const float4*)&T[1 + e0][fo + 4];
        float4 Ya = *(const float4*)&T[1 + e1][fo], Yb = *(const float4*)&T[1 + e1][fo + 4];
        short8 r;
        r[0] = (short)f2bf(Ga.x + g0 * Xa.x + g1 * Ya.x);
        r[1] = (short)f2bf(Ga.y + g0 * Xa.y + g1 * Ya.y);
        r[2] = (short)f2bf(Ga.z + g0 * Xa.z + g1 * Ya.z);
        r[3] = (short)f2bf(Ga.w + g0 * Xa.w + g1 * Ya.w);
        r[4] = (short)f2bf(Gb.x + g0 * Xb.x + g1 * Yb.x);
        r[5] = (short)f2bf(Gb.y + g0 * Xb.y + g1 * Yb.y);
        r[6] = (short)f2bf(Gb.z + g0 * Xb.z + g1 * Yb.z);
        r[7] = (short)f2bf(Gb.w + g0 * Xb.w + g1 * Yb.w);
        *(short8*)(wrow + (size_t)b * 475136) = r;
    }
}

// ---------------- Main fused batched GEMM: out[b] = x[b] @ Wcomb_b + bias ------
// R6 = R4's byte-minimal tiling (BM=128/BN=512/slab: 1.65 MB VMEM per CU, the
// minimum of all configs tried) x R3's counted-vmcnt depth pipeline (the only
// structure that ran at ~10.4 B/cy/CU; R4's __syncthreads ran at ~8).
// As[3]/Bs[3] (126 KB LDS, 1 blk/CU), 3-step buffer rotation. Per step t:
//   issue loadA(t+2) [2 ops] + stageB(t+2) [4 ops]
//   compute(t)   (MFMA from As/Bs[t%3])
//   packA(t+1)   (compiler-inserted wait on A(t+1) regs; keeps B(t+2) in flight)
//   BARN(6): s_waitcnt vmcnt(6); s_barrier  — retires exactly the PREVIOUS
//   step's 6 ops (order-robust: steps are separated by the asm barrier, which
//   loads cannot cross), so B(t+1) is guaranteed landed and B(t+2)+A(t+2) ride
//   through ~2 full compute phases. No sched_barrier pinning (m141).
// loadA(28) is branchless-uniform (always 2 loads) so vmcnt counts are exact.
__global__ __launch_bounds__(512, 1) void moe_gemm(const float* __restrict__ x,
                                                   const unsigned short* __restrict__ wc,
                                                   const float4* __restrict__ gates,
                                                   const float* __restrict__ eb,
                                                   const float* __restrict__ genb,
                                                   float* __restrict__ out) {
    __shared__ unsigned short As[3][128 * 40];   // [m][k] bf16, stride 40 (30 KB)
    __shared__ unsigned short Bs[3][512 * 32];   // [n][k] bf16, slot-swizzled (96 KB)
    const int g  = blockIdx.x;                   // 0..255
    const int b  = (g & 7) + 8 * (g >> 5);
    const int m0 = ((g >> 3) & 3) * 128;
    const int t = threadIdx.x, lane = t & 63, wid = t >> 6;
    const float4 gt = gates[b];
    const int e0 = __float_as_int(gt.x), e1 = __float_as_int(gt.y);
    const float g0 = gt.z, g1 = gt.w;
    const float* xb = x + (size_t)b * 512 * 900;
    const unsigned short* wcb = wc + (size_t)b * 475136;
    f32x4 acc[4][8];
    #pragma unroll
    for (int mi = 0; mi < 4; ++mi)
        #pragma unroll
        for (int ni = 0; ni < 8; ++ni)
            acc[mi][ni] = (f32x4){0.f, 0.f, 0.f, 0.f};

    // A staging: thread -> row t>>2 (128 rows), 8 floats at (t&3)*8
    const int arow = t >> 2;
    const int acol = (t & 3) * 8;
    const float* xrow = xb + (size_t)(m0 + arow) * 900 + acol;
    // B staging: lane -> row u=lane>>2 in 16-row chunk; slot=lane&3 holds
    // global seg = slot ^ ((u>>1)&3) = slot ^ ((lane>>3)&3)
    const int bseg  = (lane & 3) ^ ((lane >> 3) & 3);
    const int burow = lane >> 2;

    const int wm = wid >> 2;            // 0..1 : m-half
    const int wn = (wid & 3) * 128;     // n-origin of wave
    const int lm = lane & 15, lq = lane >> 4;

    auto stageB = [&](int buf, int kt) {
        const unsigned short* slab = wcb + (size_t)kt * 16384;
        #pragma unroll
        for (int r = 0; r < 4; ++r) {
            const int chunk = wid * 4 + r;
            const unsigned short* gsrc = slab + (chunk * 16 + burow) * 32 + bseg * 8;
            unsigned short* ldst = &Bs[buf][chunk * 512];
            __builtin_amdgcn_global_load_lds(
                (const __attribute__((address_space(1))) unsigned int*)gsrc,
                (__attribute__((address_space(3))) unsigned int*)ldst, 16, 0, 0);
        }
    };
    auto loadA = [&](int kt, float4& lo, float4& hi) {
        // Uniform 2 loads every call (exact vmcnt bookkeeping). kt=28 tail:
        // clamp both loads to row base + 896 (16B-aligned, in-bounds), then mask.
        const float* base = (kt < 28) ? (xrow + kt * 32)
                                      : (xb + (size_t)(m0 + arow) * 900 + 896);
        const int hoff = (kt < 28) ? 4 : 0;
        lo = *(const float4*)base;
        hi = *(const float4*)(base + hoff);
        if (kt >= 28) {
            if (acol != 0) lo = make_float4(0.f, 0.f, 0.f, 0.f);
            hi = make_float4(0.f, 0.f, 0.f, 0.f);
        }
    };
    auto packA = [&](int buf, float4 lo, float4 hi) {
        *(short8*)&As[buf][arow * 40 + acol] = pk8(lo, hi);
    };
    auto compute = [&](int buf) {
        short8 af[4];
        #pragma unroll
        for (int mi = 0; mi < 4; ++mi)
            af[mi] = *(const short8*)&As[buf][(wm * 64 + mi * 16 + lm) * 40 + lq * 8];
        #pragma unroll
        for (int ni = 0; ni < 8; ++ni) {
            const int n = wn + ni * 16 + lm;
            const int slot = lq ^ ((lm >> 1) & 3);
            short8 bf = *(const short8*)&Bs[buf][n * 32 + slot * 8];
            #pragma unroll
            for (int mi = 0; mi < 4; ++mi)
                acc[mi][ni] = __builtin_amdgcn_mfma_f32_16x16x32_bf16(
                    af[mi], bf, acc[mi][ni], 0, 0, 0);
        }
    };

#define BARN(n) asm volatile("s_waitcnt vmcnt(" #n ") lgkmcnt(0)\n\ts_barrier" ::: "memory")
#define FENCE() asm volatile("" ::: "memory")

    float4 aL, aH, nL, nH;
    // ---- prologue: land kt=0 fully (one-time drain), pre-issue step "-1"'s
    // 6 ops {A(1),B(1)} behind a reorder fence so loop-step issues stay younger.
    loadA(0, aL, aH);
    stageB(0, 0);
    packA(0, aL, aH);
    BARN(0);
    loadA(1, aL, aH);
    stageB(1, 1);
    FENCE();
    // ---- steady: t = 0..26 (9 x 3, buffer indices compile-time).
    #pragma unroll 1
    for (int q = 0; q < 9; ++q) {
        const int tb = q * 3;
        { loadA(tb + 2, nL, nH); stageB(2, tb + 2); compute(0); packA(1, aL, aH); aL = nL; aH = nH; BARN(6); }
        { loadA(tb + 3, nL, nH); stageB(0, tb + 3); compute(1); packA(2, aL, aH); aL = nL; aH = nH; BARN(6); }
        { loadA(tb + 4, nL, nH); stageB(1, tb + 4); compute(2); packA(0, aL, aH); aL = nL; aH = nH; BARN(6); }
    }
    // ---- t=27: nothing left to issue; A(28)+B(28) are the only 6 in flight.
    compute(0);                 // 27%3
    packA(1, aL, aH);           // As[28%3], waits A(28)
    BARN(0);                    // drain B(28), barrier
    // ---- t=28
    compute(1);

#undef BARN
#undef FENCE

    // ---- Epilogue: add gen_b + g0*eb[e0] + g1*eb[e1], store f32
    #pragma unroll
    for (int ni = 0; ni < 8; ++ni) {
        const int col = wn + ni * 16 + lm;
        const float bias = genb[col] + g0 * eb[e0 * 512 + col] + g1 * eb[e1 * 512 + col];
        #pragma unroll
        for (int mi = 0; mi < 4; ++mi) {
            const int row = m0 + wm * 64 + mi * 16 + lq * 4;
            #pragma unroll
            for (int r = 0; r < 4; ++r)
                out[((size_t)b * 512 + row + r) * 512 + col] = acc[mi][ni][r] + bias;
        }
    }
}

extern "C" void kernel_launch(void* const* d_in, const int* in_sizes, int n_in,
                              void* d_out, int out_size, void* d_ws, size_t ws_size,
                              hipStream_t stream) {
    const float* x    = (const float*)d_in[0];   // [64][512][900]
    const float* cyc  = (const float*)d_in[1];   // [64][1]
    const float* dkp  = (const float*)d_in[2];   // [64][4096]
    const float* gW1  = (const float*)d_in[3];   // [4097][2048]
    const float* gb1  = (const float*)d_in[4];   // [2048]
    const float* gW2  = (const float*)d_in[5];   // [2048][8]
    const float* gb2  = (const float*)d_in[6];   // [8]
    const float* eW   = (const float*)d_in[7];   // [8][900][512]
    const float* eb   = (const float*)d_in[8];   // [8][512]
    const float* genW = (const float*)d_in[9];   // [900][512]
    const float* genb = (const float*)d_in[10];  // [512]
    float* out = (float*)d_out;                  // [64][512][512] f32

    char* ws = (char*)d_ws;
    const size_t WCOMB_BYTES = 60817408ull;              // [64][29][512][32] bf16
    const size_t PART_BYTES  = 64ull * 64 * 2048 * 4;    // 33.5 MB
    unsigned short* wcomb = (unsigned short*)ws;
    float* part; float4* gts; float* plog;
    if (ws_size >= WCOMB_BYTES + PART_BYTES + (1u << 20)) {
        // un-aliased: avoids cross-XCD dirty-line ping-pong between router1's
        // part writes and combine_w's wcomb rewrites of the same lines.
        part = (float*)(ws + WCOMB_BYTES);
        gts  = (float4*)(ws + WCOMB_BYTES + PART_BYTES);
        plog = (float*)(ws + WCOMB_BYTES + PART_BYTES + 1024);
    } else {
        // fallback: partials alias wcomb (dead before combine_w runs)
        part = (float*)ws;
        gts  = (float4*)(ws + WCOMB_BYTES);
        plog = (float*)(ws + WCOMB_BYTES + 1024);
    }

    router1<<<512, 256, 0, stream>>>(dkp, gW1, part);
    router2p<<<dim3(64, 8), 256, 0, stream>>>(part, cyc, gW1, gb1, gW2, plog);
    combine_w<<<dim3(16, 29), 256, 0, stream>>>(genW, eW, plog, gb2, gts, wcomb);
    moe_gemm<<<256, 512, 0, stream>>>(x, wcomb, gts, eb, genb, out);
}